// Round 16
// baseline (814.685 us; speedup 1.0000x reference)
//
#include <hip/hip_runtime.h>
#include <hip/hip_bf16.h>
#include <stdint.h>

#define BB 4
#define TT 100
#define DD 256
#define LL 256
#define NF (BB*TT)          // 400 frames
#define FRAME (DD*LL)       // 65536 elements per frame (ch * spatial)
#define EPSB 1e-5f

#define S1_N 2304           // k_prep: wr2 reorder blocks
#define S2_N 1024           // k_prep: wcomb rows
// k_prep stage layout: [0,S1_N) wr2 | [S1_N,S1_N+S2_N) wcomb | S1_N+S2_N out-init
//                      | [S1_N+S2_N+1, +NF) cam transpose->bf16 (only if camT fits ws)
// R16: stages launched separately (bid0 offset) purely for top-5 attribution.

typedef __bf16  bf16x8 __attribute__((ext_vector_type(8)));
typedef float   f32x4  __attribute__((ext_vector_type(4)));
typedef int     i32x4  __attribute__((ext_vector_type(4)));

__device__ __forceinline__ float bf2f(unsigned short u){
    return __uint_as_float(((unsigned int)u) << 16);
}
__device__ __forceinline__ unsigned short f2bf(float f){
    __hip_bfloat16 h = __float2bfloat16(f);
    return *reinterpret_cast<unsigned short*>(&h);
}
__device__ __forceinline__ float fsigm(float x){ return 1.0f/(1.0f + __expf(-x)); }
__device__ __forceinline__ float ftanh(float x){
    x = fminf(fmaxf(x, -15.f), 15.f);
    float e = __expf(2.f*x);
    return (e - 1.f) / (e + 1.f);
}
__device__ __forceinline__ int8_t q8(float x){
    int v = (int)lrintf(x);
    v = v < -127 ? -127 : (v > 127 ? 127 : v);
    return (int8_t)v;
}

// scan W_comb col slot mapping: gate row r=g*256+u; u=wv*32+e*16+n; ct=g*2+e
__device__ __forceinline__ size_t wq_off(int r, int k){
    int g = r >> 8, u = r & 255;
    int wv = u >> 5, e = (u >> 4) & 1, n = u & 15;
    int ct = g*2 + e;
    int kt = k >> 6, quad = (k >> 4) & 3, j = k & 15;
    return ((size_t)(((wv*8 + ct)*4 + kt)*4 + quad)*16 + n)*16 + j;
}

// ================= K_PREP: wr2-reorder + wcomb-quant + wihT + cam transpose + out init ===
__global__ __launch_bounds__(256) void k_prep(const float* __restrict__ convw,
                                              const float* __restrict__ wih,
                                              const float* __restrict__ whh,
                                              const float* __restrict__ ww,
                                              const float* __restrict__ wb,
                                              const float* __restrict__ bih,
                                              const float* __restrict__ bhh,
                                              const float* __restrict__ woutb,
                                              const float* __restrict__ cam,
                                              unsigned short* __restrict__ wr2,
                                              int8_t* __restrict__ Wq,
                                              float* __restrict__ dqs,
                                              float* __restrict__ biasg,
                                              float* __restrict__ wihT,
                                              unsigned short* __restrict__ camT,
                                              float* __restrict__ out,
                                              int bid0){
    const int bid = blockIdx.x + bid0, tid = threadIdx.x;
    __shared__ float wihL[256];
    __shared__ float red[4];
    __shared__ float smaxs;
    __shared__ unsigned short tileL[64][66];   // transpose tile (+2 pad: 2-way max, free)
    if (bid < S1_N){
        // wr2[tap][oc][ic] bf16 from convw OIHW fp32
        int idx = bid*256 + tid;                 // 0..589823
        int i  = idx & 255;
        int rest = idx >> 8;
        int o  = rest & 255;
        int t9 = rest >> 8;
        wr2[idx] = f2bf(convw[((o<<8) + i)*9 + t9]);
    } else if (bid < S1_N + S2_N){
        // W_comb = whh + wih@w_w -> int8 frag-packed, dq scales, fused bias
        const int r = bid - S1_N;
        const int lane = tid&63, wave = tid>>6;
        wihL[tid] = wih[r*256+tid];
        // wihT[k][r] transpose for k_frame2 broadcast-GEMV
        wihT[(size_t)tid*1024 + r] = wihL[tid];
        __syncthreads();
        float acc = whh[r*256+tid];
        for (int k=0;k<256;++k) acc = fmaf(wihL[k], ww[k*256+tid], acc);
        float m = fabsf(acc);
#pragma unroll
        for (int off=32; off; off>>=1) m = fmaxf(m, __shfl_down(m,off,64));
        if (lane==0) red[wave] = m;
        __syncthreads();
        if (tid==0){
            float s = fmaxf(fmaxf(red[0],red[1]),fmaxf(red[2],red[3]));
            smaxs = (s > 1e-30f) ? s : 1.0f;
            dqs[r] = smaxs * (1.0f/16129.0f);    // smax/(127*127)
        }
        __syncthreads();
        float inv = 127.0f / smaxs;
        Wq[wq_off(r, tid)] = q8(acc * inv);
        if (tid < 64){
            float s = 0.f;
#pragma unroll
            for (int q=0;q<4;++q) s += wihL[tid + 64*q] * wb[tid + 64*q];
#pragma unroll
            for (int off=32; off; off>>=1) s += __shfl_down(s,off,64);
            if (tid==0) biasg[r] = bih[r] + bhh[r] + s;
        }
    } else if (bid == S1_N + S2_N){
        for (int i=tid; i<800; i+=256) out[i] = woutb[i & 1];
    } else {
        // cam[f][c][sp] f32 -> camT[f][sp][c] bf16, 64x64 LDS tile transpose
        const int f = bid - (S1_N + S2_N + 1);
        const int wave = tid>>6, lane = tid&63;
        const float* src = cam + (size_t)f*FRAME;
        unsigned short* dst = camT + (size_t)f*FRAME;
        for (int tc=0; tc<4; ++tc)
        for (int ts=0; ts<4; ++ts){
            const int c0t = tc*64, s0t = ts*64;
#pragma unroll
            for (int i=0;i<16;++i)
                tileL[wave*16+i][lane] = f2bf(src[(size_t)(c0t+wave*16+i)*256 + s0t + lane]);
            __syncthreads();
#pragma unroll
            for (int i=0;i<16;++i)
                dst[(size_t)(s0t+wave*16+i)*256 + c0t + lane] = tileL[lane][wave*16+i];
            __syncthreads();
        }
    }
}

// ================= K_CONV2: conv3x3 via MFMA + fused BN partials =================
// grid (4, 100) x4 launches (f0 = 0,100,200,300). R4-proven structure (163.8us
// full-grid). Quartered purely for top-5 attribution (threshold ~41us).
// XSTR=40 is the measured optimum (36: misaligned+spill -> 283us. DO NOT TOUCH).
#define XSTR 40
__global__ __launch_bounds__(256, 3) void k_conv2(const float* __restrict__ cam,
                                                  const unsigned short* __restrict__ camT,
                                                  const unsigned short* __restrict__ wr,
                                                  const float* __restrict__ cb,
                                                  unsigned short* __restrict__ y,
                                                  float* __restrict__ Sp,
                                                  float* __restrict__ Sq,
                                                  int f0){
    const int f   = blockIdx.y + f0;
    const int oc0 = blockIdx.x * 64;
    const int tid = threadIdx.x;
    const int wv    = tid >> 6;
    const int quad  = (tid >> 4) & 3;
    const int wlane = tid & 15;

    __shared__ __align__(16) unsigned short Xl[324*XSTR];
    __shared__ __align__(16) unsigned short Al[192*XSTR];
    __shared__ float SredS[64], SredQ[64];

    for (int i = tid; i < 324*XSTR/2; i += 256) ((unsigned int*)Xl)[i] = 0u;
    if (tid < 64){ SredS[tid]=0.f; SredQ[tid]=0.f; }

    f32x4 acc[4][4];
#pragma unroll
    for (int mt=0; mt<4; ++mt){
        const int oc = oc0 + mt*16 + quad*4;
        f32x4 bv; bv[0]=cb[oc]; bv[1]=cb[oc+1]; bv[2]=cb[oc+2]; bv[3]=cb[oc+3];
#pragma unroll
        for (int nt=0; nt<4; ++nt) acc[mt][nt] = bv;
    }

    const int sp  = tid;
    const int spp = ((sp>>4)+1)*18 + (sp&15) + 1;
    const float* xs = cam + ((size_t)f*256)*256 + sp;
    const unsigned short* xt = camT ? (camT + (size_t)f*FRAME + (size_t)sp*256) : nullptr;

    for (int ck=0; ck<8; ++ck){
        const int c0 = ck*32;
        for (int tg=0; tg<3; ++tg){
            __syncthreads();
            if (tg == 0){
                if (xt){
                    // pre-converted bf16, channel-contiguous: 4 x 16B loads, zero VALU
                    const uint4* xc4 = (const uint4*)(xt + c0);
#pragma unroll
                    for (int jb=0; jb<4; ++jb)
                        *(uint4*)&Xl[spp*XSTR + jb*8] = xc4[jb];
                } else {
                    // fallback: fp32 gather + in-register convert (ws too small for camT)
                    const float* xc = xs + (size_t)c0*256;
#pragma unroll
                    for (int jb=0; jb<4; ++jb){
                        unsigned int q0,q1,q2,q3;
                        {
                            float a0=xc[(jb*8+0)*256], a1=xc[(jb*8+1)*256];
                            float a2=xc[(jb*8+2)*256], a3=xc[(jb*8+3)*256];
                            float a4=xc[(jb*8+4)*256], a5=xc[(jb*8+5)*256];
                            float a6=xc[(jb*8+6)*256], a7=xc[(jb*8+7)*256];
                            q0 = (unsigned int)f2bf(a0) | ((unsigned int)f2bf(a1)<<16);
                            q1 = (unsigned int)f2bf(a2) | ((unsigned int)f2bf(a3)<<16);
                            q2 = (unsigned int)f2bf(a4) | ((unsigned int)f2bf(a5)<<16);
                            q3 = (unsigned int)f2bf(a6) | ((unsigned int)f2bf(a7)<<16);
                        }
                        uint4 qv; qv.x=q0; qv.y=q1; qv.z=q2; qv.w=q3;
                        *(uint4*)&Xl[spp*XSTR + jb*8] = qv;
                    }
                }
            }
            if (tid < 192){
                const unsigned short* src = wr +
                    ((size_t)((tg*3 + (tid>>6))*256 + oc0 + (tid&63)))*256 + c0;
                const uint4* s4 = (const uint4*)src;
                uint4* dq = (uint4*)(Al + tid*XSTR);
                dq[0]=s4[0]; dq[1]=s4[1]; dq[2]=s4[2]; dq[3]=s4[3];
            }
            __syncthreads();
#pragma unroll
            for (int cc=0; cc<3; ++cc){
                bf16x8 af[4], bfr[4];
#pragma unroll
                for (int mt=0; mt<4; ++mt)
                    af[mt] = *(const bf16x8*)(Al + ((cc*64 + mt*16 + wlane)*XSTR + quad*8));
#pragma unroll
                for (int nt=0; nt<4; ++nt){
                    const int hh = wv*4 + nt;
                    const int pp = (hh + tg)*18 + wlane + cc;
                    bfr[nt] = *(const bf16x8*)(Xl + (pp*XSTR + quad*8));
                }
#pragma unroll
                for (int mt=0; mt<4; ++mt)
#pragma unroll
                    for (int nt=0; nt<4; ++nt)
                        acc[mt][nt] = __builtin_amdgcn_mfma_f32_16x16x32_bf16(
                            af[mt], bfr[nt], acc[mt][nt], 0, 0, 0);
            }
        }
    }

    // epilogue: y store (C/D layout col=lane&15, row=(lane>>4)*4+reg) [m89-verified]
#pragma unroll
    for (int mt=0; mt<4; ++mt){
        const int oc = oc0 + mt*16 + quad*4;
#pragma unroll
        for (int nt=0; nt<4; ++nt){
            const int p = (wv*4 + nt)*16 + wlane;
#pragma unroll
            for (int reg=0; reg<4; ++reg)
                y[((size_t)(f*256) + oc + reg)*256 + p] = f2bf(acc[mt][nt][reg]);
        }
    }
    // fused BN partial sums: per-(f,oc) sum over 256 spatial
    __syncthreads();
#pragma unroll
    for (int mt=0; mt<4; ++mt){
#pragma unroll
        for (int reg=0; reg<4; ++reg){
            float s=0.f, q=0.f;
#pragma unroll
            for (int nt=0; nt<4; ++nt){ float v=acc[mt][nt][reg]; s+=v; q+=v*v; }
#pragma unroll
            for (int off=1; off<16; off<<=1){ s += __shfl_xor(s,off,64); q += __shfl_xor(q,off,64); }
            if (wlane==0){
                atomicAdd(&SredS[mt*16 + quad*4 + reg], s);
                atomicAdd(&SredQ[mt*16 + quad*4 + reg], q);
            }
        }
    }
    __syncthreads();
    if (tid < 64){
        Sp[f*256 + oc0 + tid] = SredS[tid];
        Sq[f*256 + oc0 + tid] = SredQ[tid];
    }
}

// ================= K_BNFIN: finish BN stats -> scale/shift =================
__global__ __launch_bounds__(64) void k_bnfin(const float* __restrict__ Sp,
                                              const float* __restrict__ Sq,
                                              const float* __restrict__ gamma,
                                              const float* __restrict__ beta,
                                              float* __restrict__ scale,
                                              float* __restrict__ shift){
    const int c = blockIdx.x, lane = threadIdx.x;
    float s = 0.f, q = 0.f;
    for (int f=lane; f<NF; f+=64){ s += Sp[f*256 + c]; q += Sq[f*256 + c]; }
#pragma unroll
    for (int off=32; off; off>>=1){ s += __shfl_down(s,off,64); q += __shfl_down(q,off,64); }
    if (lane==0){
        const float invN = 1.0f/(float)(NF*256);
        float mean = s*invN;
        float var  = q*invN - mean*mean;
        float istd = rsqrtf(var + EPSB);
        float sc = gamma[c]*istd;
        scale[c] = sc;
        shift[c] = beta[c] - mean*sc;
    }
}

// ================= K_FRAME2: softmax/alpha/logp + ctx + x0 + fused Gp build =================
// R16: f0 offset, 2 half-launches for attribution.
__global__ __launch_bounds__(256) void k_frame2(const unsigned short* __restrict__ y,
                                                const float* __restrict__ scale,
                                                const float* __restrict__ shift,
                                                const float* __restrict__ wattn,
                                                const float* __restrict__ wihT,
                                                float* __restrict__ d_out,
                                                float* __restrict__ Gp,
                                                float* __restrict__ x0g,
                                                int f0){
    const int f = blockIdx.x + f0, tid = threadIdx.x;
    const int b = f / TT, t = f - b*TT;
    const int wave = tid>>6, lane = tid&63;
    __shared__ float fdotL[256], alphaL[256], x0acc[256], wattnL[256];
    __shared__ float ctxP[4][256];
    __shared__ float redM[4], redS[4];
    wattnL[tid] = wattn[tid];
    x0acc[tid] = 0.f;
    __syncthreads();
    const bool isT0 = (t==0);
    const float wl0 = wattnL[lane*4+0], wl1 = wattnL[lane*4+1];
    const float wl2 = wattnL[lane*4+2], wl3 = wattnL[lane*4+3];
    const ushort4* y4 = (const ushort4*)(y + (size_t)f*FRAME);
    for (int ci=0; ci<64; ++ci){
        int c = wave + ci*4;
        ushort4 u = y4[c*64 + lane];
        float sc = scale[c], sh = shift[c];
        float v0 = fmaxf(fmaf(bf2f(u.x),sc,sh),0.f);
        float v1 = fmaxf(fmaf(bf2f(u.y),sc,sh),0.f);
        float v2 = fmaxf(fmaf(bf2f(u.z),sc,sh),0.f);
        float v3 = fmaxf(fmaf(bf2f(u.w),sc,sh),0.f);
        float s = v0*wl0 + v1*wl1 + v2*wl2 + v3*wl3;
#pragma unroll
        for (int off=32; off; off>>=1) s += __shfl_down(s,off,64);
        if (lane==0) fdotL[c] = s;
        if (isT0){
            atomicAdd(&x0acc[lane*4+0], v0);
            atomicAdd(&x0acc[lane*4+1], v1);
            atomicAdd(&x0acc[lane*4+2], v2);
            atomicAdd(&x0acc[lane*4+3], v3);
        }
    }
    __syncthreads();
    float v = fdotL[tid];
    float m = v;
#pragma unroll
    for (int off=32; off; off>>=1) m = fmaxf(m, __shfl_down(m,off,64));
    if (lane==0) redM[wave]=m;
    __syncthreads();
    m = fmaxf(fmaxf(redM[0],redM[1]),fmaxf(redM[2],redM[3]));
    float e = __expf(v-m);
    float ss = e;
#pragma unroll
    for (int off=32; off; off>>=1) ss += __shfl_down(ss,off,64);
    if (lane==0) redS[wave]=ss;
    __syncthreads();
    float S = redS[0]+redS[1]+redS[2]+redS[3];
    float logS = logf(S);
    float alpha = e / S;
    d_out[800    + ((t*BB)+b)*256 + tid] = alpha;
    d_out[103200 + ((t*BB)+b)*256 + tid] = v - m - logS;
    alphaL[tid] = alpha;
    if (isT0) x0g[b*256+tid] = x0acc[tid];
    __syncthreads();
    // ctx pass: wave-partial over 64 channels, vectorized ushort4, 4-way LDS reduce
    {
        float ca0=0.f, ca1=0.f, ca2=0.f, ca3=0.f;
        for (int ci=0; ci<64; ++ci){
            int c = wave + ci*4;
            ushort4 u = y4[c*64 + lane];
            float sc = scale[c], sh = shift[c];
            float al = alphaL[c];
            ca0 = fmaf(fmaxf(fmaf(bf2f(u.x),sc,sh),0.f), al, ca0);
            ca1 = fmaf(fmaxf(fmaf(bf2f(u.y),sc,sh),0.f), al, ca1);
            ca2 = fmaf(fmaxf(fmaf(bf2f(u.z),sc,sh),0.f), al, ca2);
            ca3 = fmaf(fmaxf(fmaf(bf2f(u.w),sc,sh),0.f), al, ca3);
        }
        ctxP[wave][lane*4+0] = ca0;
        ctxP[wave][lane*4+1] = ca1;
        ctxP[wave][lane*4+2] = ca2;
        ctxP[wave][lane*4+3] = ca3;
    }
    __syncthreads();
    fdotL[tid] = ctxP[0][tid] + ctxP[1][tid] + ctxP[2][tid] + ctxP[3][tid];
    __syncthreads();
    // fused gperm via wihT broadcast-GEMV: thread owns rows tid*4..tid*4+3.
    float accg[4] = {0.f, 0.f, 0.f, 0.f};
    const float4* wT4 = (const float4*)wihT;
#pragma unroll 8
    for (int k=0; k<256; ++k){
        float ck = fdotL[k];
        float4 wv = wT4[k*256 + tid];
        accg[0] = fmaf(ck, wv.x, accg[0]);
        accg[1] = fmaf(ck, wv.y, accg[1]);
        accg[2] = fmaf(ck, wv.z, accg[2]);
        accg[3] = fmaf(ck, wv.w, accg[3]);
    }
    float* gout = Gp + (size_t)t*4096;
#pragma unroll
    for (int j=0; j<4; ++j){
        int r = tid*4 + j;
        int g = r >> 8, u = r & 255;
        int wvv = u >> 5, e = (u >> 4) & 1, nn = u & 15;
        gout[(wvv*64 + b*16 + nn)*8 + e*4 + g] = accg[j];
    }
}

// ================= K_INIT: hx/cx = tanh(x0 @ W.T + b) =================
__global__ __launch_bounds__(256) void k_init(const float* __restrict__ x0g,
                                              const float* __restrict__ ihw,
                                              const float* __restrict__ ihb,
                                              const float* __restrict__ icw,
                                              const float* __restrict__ icb,
                                              float* __restrict__ hxg,
                                              float* __restrict__ cxg){
    const int b = blockIdx.x >> 1, which = blockIdx.x & 1;
    const int tid = threadIdx.x, wave = tid>>6, lane = tid&63;
    __shared__ float xL[256];
    xL[tid] = x0g[b*256+tid] * (1.0f/256.0f);
    __syncthreads();
    const float* wmat = which ? icw : ihw;
    const float* bias = which ? icb : ihb;
    float* dst = which ? cxg : hxg;
    const float4* x4 = (const float4*)xL;
    float4 xv = x4[lane];
    const float4* w4 = (const float4*)wmat;
    for (int r=wave; r<256; r+=4){
        float4 wv = w4[r*64+lane];
        float s = xv.x*wv.x + xv.y*wv.y + xv.z*wv.z + xv.w*wv.w;
#pragma unroll
        for (int off=32; off; off>>=1) s += __shfl_down(s,off,64);
        if (lane==0) dst[b*256+r] = tanhf(s + bias[r]);
    }
}

// ================= K_SCAN: single-WG persistent LSTM scan — 16 waves, predL (best) ===
// Measured: 8-wave predL 142us; 16-wave predL 132us (BEST); global-hist 142us (vmcnt
// drain at barrier — reverted). This is the 132us version.
__global__ __launch_bounds__(1024) void k_scan(const int8_t* __restrict__ Wq,
                                               const float* __restrict__ dqs,
                                               const float* __restrict__ biasg,
                                               const float* __restrict__ Gp,
                                               const float* __restrict__ cxg,
                                               const float* __restrict__ hxg,
                                               const float* __restrict__ woutw,
                                               float* __restrict__ out){
    const int tid  = threadIdx.x;
    const int wv2  = tid >> 6, lane = tid & 63;
    const int q    = lane >> 4, n = lane & 15;
    const int w8   = wv2 >> 1, e = wv2 & 1;

    __shared__ __align__(16) int8_t hxq[2][4*272];
    __shared__ float predL[TT*128];   // [t][wv2*8 + q*2 + j], per-wave slots (no races)

    // unit owned by this lane
    const int u = w8*32 + e*16 + n;

    i32x4 bfrag[4][4];
#pragma unroll
    for (int g=0; g<4; ++g)
#pragma unroll
        for (int kt=0; kt<4; ++kt)
            bfrag[g][kt] = *(const i32x4*)(Wq +
                ((size_t)(((w8*8 + g*2 + e)*4 + kt)*4 + q)*16 + n)*16);

    float cx = cxg[q*256 + u];
    const float w0 = woutw[u], w1 = woutw[256 + u];
    float dq[4], bb[4];
#pragma unroll
    for (int g=0; g<4; ++g){
        dq[g] = dqs[g*256 + u];
        bb[g] = biasg[g*256 + u];
    }

    {
        const int b0 = tid >> 8, u0 = tid & 255;
        hxq[0][b0*272 + u0] = q8(hxg[b0*256 + u0] * 127.0f);
    }
    const size_t gbase = (size_t)((w8*64 + q*16 + n)*8 + e*4);
    float4 gA = *(const float4*)(Gp + gbase);
    __syncthreads();

    for (int t=0; t<TT; ++t){
        const int tn = (t+1 < TT) ? t+1 : t;
        float4 nA = *(const float4*)(Gp + (size_t)tn*4096 + gbase);

        const int8_t* hb = hxq[t & 1];
        i32x4 afr[4];
#pragma unroll
        for (int kt=0; kt<4; ++kt)
            afr[kt] = *(const i32x4*)(hb + (n >> 2)*272 + kt*64 + q*16);

        i32x4 acc[4];
#pragma unroll
        for (int g=0; g<4; ++g){ acc[g][0]=0; acc[g][1]=0; acc[g][2]=0; acc[g][3]=0; }
#pragma unroll
        for (int g=0; g<4; ++g)
#pragma unroll
            for (int kt=0; kt<4; ++kt)
                acc[g] = __builtin_amdgcn_mfma_i32_16x16x64_i8(afr[kt], bfrag[g][kt], acc[g], 0, 0, 0);

        float gi = (float)acc[0][0]*dq[0] + gA.x + bb[0];
        float gf = (float)acc[1][0]*dq[1] + gA.y + bb[1];
        float gg = (float)acc[2][0]*dq[2] + gA.z + bb[2];
        float go = (float)acc[3][0]*dq[3] + gA.w + bb[3];

        float cn = fsigm(gf)*cx + fsigm(gi)*ftanh(gg);
        float hn = fsigm(go)*ftanh(cn);
        cx = cn;

        hxq[(t+1) & 1][q*272 + u] = q8(hn * 127.0f);

        float p0 = hn*w0;
        float p1 = hn*w1;
#pragma unroll
        for (int off=1; off<16; off<<=1){
            p0 += __shfl_xor(p0, off, 64);
            p1 += __shfl_xor(p1, off, 64);
        }
        if (n == 0){
            predL[t*128 + wv2*8 + q*2 + 0] = p0;
            predL[t*128 + wv2*8 + q*2 + 1] = p1;
        }
        gA = nA;
        __syncthreads();
    }
    // epilogue: reduce per-wave slots -> out (out pre-loaded with woutb by k_prep)
    if (tid < TT*8){
        const int t = tid >> 3, j = tid & 7;
        float s = 0.f;
#pragma unroll
        for (int w16 = 0; w16 < 16; ++w16) s += predL[t*128 + w16*8 + j];
        out[tid] += s;
    }
}

extern "C" void kernel_launch(void* const* d_in, const int* in_sizes, int n_in,
                              void* d_out, int out_size, void* d_ws, size_t ws_size,
                              hipStream_t stream){
    const float* cam   = (const float*)d_in[0];
    const float* convw = (const float*)d_in[1];
    const float* convb = (const float*)d_in[2];
    const float* gamma = (const float*)d_in[3];
    const float* beta  = (const float*)d_in[4];
    const float* ihw   = (const float*)d_in[5];
    const float* ihb   = (const float*)d_in[6];
    const float* icw   = (const float*)d_in[7];
    const float* icb   = (const float*)d_in[8];
    const float* ww    = (const float*)d_in[9];
    const float* wb    = (const float*)d_in[10];
    const float* wattn = (const float*)d_in[11];
    // d_in[12] = wattn_b: unused (softmax is shift-invariant)
    const float* wih   = (const float*)d_in[13];
    const float* whh   = (const float*)d_in[14];
    const float* bih   = (const float*)d_in[15];
    const float* bhh   = (const float*)d_in[16];
    const float* woutw = (const float*)d_in[17];
    const float* woutb = (const float*)d_in[18];
    float* out = (float*)d_out;

    char* wsb = (char*)d_ws;
    size_t off = 0;
    auto alloc = [&](size_t bytes)->void*{
        void* p = wsb + off; off += (bytes + 255) & ~(size_t)255; return p;
    };
    unsigned short* y   = (unsigned short*)alloc((size_t)NF*FRAME*2);
    unsigned short* wr2 = (unsigned short*)alloc((size_t)589824*2);
    int8_t* Wq      = (int8_t*)alloc((size_t)262144);
    float* dqs      = (float*)alloc(1024*4);
    float* Sp       = (float*)alloc((size_t)NF*256*4);
    float* Sq       = (float*)alloc((size_t)NF*256*4);
    float* scale    = (float*)alloc(256*4);
    float* shift    = (float*)alloc(256*4);
    float* x0g      = (float*)alloc(1024*4);
    float* Gp       = (float*)alloc((size_t)TT*4096*4);
    float* biasg    = (float*)alloc(1024*4);
    float* hxg      = (float*)alloc(1024*4);
    float* cxg      = (float*)alloc(1024*4);
    float* wihT     = (float*)alloc((size_t)262144*4);   // [k=256][r=1024] transpose
    // camT only if workspace allows (52.4 MB): guarded fallback keeps correctness
    unsigned short* camT = nullptr;
    if (ws_size >= off + (size_t)NF*FRAME*2 + 256)
        camT = (unsigned short*)alloc((size_t)NF*FRAME*2);

    // R16 attribution: prep stages, conv quarters, frame2 halves as separate launches.
    hipLaunchKernelGGL(k_prep, dim3(S1_N), dim3(256), 0, stream,
                       convw, wih, whh, ww, wb, bih, bhh, woutb, cam,
                       wr2, Wq, dqs, biasg, wihT, camT, out, 0);
    hipLaunchKernelGGL(k_prep, dim3(S2_N + 1), dim3(256), 0, stream,
                       convw, wih, whh, ww, wb, bih, bhh, woutb, cam,
                       wr2, Wq, dqs, biasg, wihT, camT, out, S1_N);
    if (camT)
        hipLaunchKernelGGL(k_prep, dim3(NF), dim3(256), 0, stream,
                           convw, wih, whh, ww, wb, bih, bhh, woutb, cam,
                           wr2, Wq, dqs, biasg, wihT, camT, out, S1_N + S2_N + 1);
    hipLaunchKernelGGL(k_conv2, dim3(4, NF/4), dim3(256), 0, stream, cam, camT, wr2, convb, y, Sp, Sq, 0);
    hipLaunchKernelGGL(k_conv2, dim3(4, NF/4), dim3(256), 0, stream, cam, camT, wr2, convb, y, Sp, Sq, 100);
    hipLaunchKernelGGL(k_conv2, dim3(4, NF/4), dim3(256), 0, stream, cam, camT, wr2, convb, y, Sp, Sq, 200);
    hipLaunchKernelGGL(k_conv2, dim3(4, NF/4), dim3(256), 0, stream, cam, camT, wr2, convb, y, Sp, Sq, 300);
    hipLaunchKernelGGL(k_bnfin, dim3(256), dim3(64), 0, stream, Sp, Sq, gamma, beta, scale, shift);
    hipLaunchKernelGGL(k_frame2, dim3(NF/2), dim3(256), 0, stream, y, scale, shift, wattn, wihT, out, Gp, x0g, 0);
    hipLaunchKernelGGL(k_frame2, dim3(NF/2), dim3(256), 0, stream, y, scale, shift, wattn, wihT, out, Gp, x0g, 200);
    hipLaunchKernelGGL(k_init, dim3(8), dim3(256), 0, stream, x0g, ihw, ihb, icw, icb, hxg, cxg);
    hipLaunchKernelGGL(k_scan, dim3(1), dim3(1024), 0, stream,
                       Wq, dqs, biasg, Gp, cxg, hxg, woutw, out);
}

// Round 17
// 666.191 us; speedup vs baseline: 1.2229x; 1.2229x over previous
//
#include <hip/hip_runtime.h>
#include <hip/hip_bf16.h>
#include <stdint.h>

#define BB 4
#define TT 100
#define DD 256
#define LL 256
#define NF (BB*TT)          // 400 frames
#define FRAME (DD*LL)       // 65536 elements per frame (ch * spatial)
#define EPSB 1e-5f

#define S1_N 576            // k_prep: wr2 reorder blocks (4 elems/thread, ushort4 stores)
#define S2_N 1024           // k_prep: wcomb rows
// k_prep stage layout: [0,S1_N) wr2 | [S1_N,S1_N+S2_N) wcomb | S1_N+S2_N out-init
//                      | [S1_N+S2_N+1, +NF) cam transpose->bf16 (only if camT fits ws)

typedef __bf16  bf16x8 __attribute__((ext_vector_type(8)));
typedef float   f32x4  __attribute__((ext_vector_type(4)));
typedef int     i32x4  __attribute__((ext_vector_type(4)));

__device__ __forceinline__ float bf2f(unsigned short u){
    return __uint_as_float(((unsigned int)u) << 16);
}
__device__ __forceinline__ unsigned short f2bf(float f){
    __hip_bfloat16 h = __float2bfloat16(f);
    return *reinterpret_cast<unsigned short*>(&h);
}
__device__ __forceinline__ float fsigm(float x){ return 1.0f/(1.0f + __expf(-x)); }
__device__ __forceinline__ float ftanh(float x){
    x = fminf(fmaxf(x, -15.f), 15.f);
    float e = __expf(2.f*x);
    return (e - 1.f) / (e + 1.f);
}
__device__ __forceinline__ int8_t q8(float x){
    int v = (int)lrintf(x);
    v = v < -127 ? -127 : (v > 127 ? 127 : v);
    return (int8_t)v;
}

// scan W_comb col slot mapping: gate row r=g*256+u; u=wv*32+e*16+n; ct=g*2+e
__device__ __forceinline__ size_t wq_off(int r, int k){
    int g = r >> 8, u = r & 255;
    int wv = u >> 5, e = (u >> 4) & 1, n = u & 15;
    int ct = g*2 + e;
    int kt = k >> 6, quad = (k >> 4) & 3, j = k & 15;
    return ((size_t)(((wv*8 + ct)*4 + kt)*4 + quad)*16 + n)*16 + j;
}

// ================= K_PREP: wr2-reorder + wcomb-quant + wihT + cam transpose + out init ===
__global__ __launch_bounds__(256) void k_prep(const float* __restrict__ convw,
                                              const float* __restrict__ wih,
                                              const float* __restrict__ whh,
                                              const float* __restrict__ ww,
                                              const float* __restrict__ wb,
                                              const float* __restrict__ bih,
                                              const float* __restrict__ bhh,
                                              const float* __restrict__ woutb,
                                              const float* __restrict__ cam,
                                              unsigned short* __restrict__ wr2,
                                              int8_t* __restrict__ Wq,
                                              float* __restrict__ dqs,
                                              float* __restrict__ biasg,
                                              float* __restrict__ wihT,
                                              unsigned short* __restrict__ camT,
                                              float* __restrict__ out){
    const int bid = blockIdx.x, tid = threadIdx.x;
    __shared__ float wihL[256];
    __shared__ float red[4];
    __shared__ float smaxs;
    __shared__ unsigned short tileL[64][66];   // transpose tile (+2 pad: 2-way max, free)
    if (bid < S1_N){
        // wr2[tap][oc][ic] bf16 from convw OIHW fp32 — 4 elems/thread, ushort4 store
        int base = (bid*256 + tid)*4;            // 0..589820, multiple of 4
        int i  = base & 255;
        int rest = base >> 8;
        int o  = rest & 255;
        int t9 = rest >> 8;
        const float* src = convw + ((size_t)((o<<8) + i))*9 + t9;
        ushort4 v;
        v.x = f2bf(src[0*9]);
        v.y = f2bf(src[1*9]);
        v.z = f2bf(src[2*9]);
        v.w = f2bf(src[3*9]);
        *(ushort4*)(wr2 + base) = v;
    } else if (bid < S1_N + S2_N){
        // W_comb = whh + wih@w_w -> int8 frag-packed, dq scales, fused bias
        const int r = bid - S1_N;
        const int lane = tid&63, wave = tid>>6;
        wihL[tid] = wih[r*256+tid];
        // wihT[k][r] transpose for k_frame2 broadcast-GEMV
        wihT[(size_t)tid*1024 + r] = wihL[tid];
        __syncthreads();
        float acc = whh[r*256+tid];
        for (int k=0;k<256;++k) acc = fmaf(wihL[k], ww[k*256+tid], acc);
        float m = fabsf(acc);
#pragma unroll
        for (int off=32; off; off>>=1) m = fmaxf(m, __shfl_down(m,off,64));
        if (lane==0) red[wave] = m;
        __syncthreads();
        if (tid==0){
            float s = fmaxf(fmaxf(red[0],red[1]),fmaxf(red[2],red[3]));
            smaxs = (s > 1e-30f) ? s : 1.0f;
            dqs[r] = smaxs * (1.0f/16129.0f);    // smax/(127*127)
        }
        __syncthreads();
        float inv = 127.0f / smaxs;
        Wq[wq_off(r, tid)] = q8(acc * inv);
        if (tid < 64){
            float s = 0.f;
#pragma unroll
            for (int q=0;q<4;++q) s += wihL[tid + 64*q] * wb[tid + 64*q];
#pragma unroll
            for (int off=32; off; off>>=1) s += __shfl_down(s,off,64);
            if (tid==0) biasg[r] = bih[r] + bhh[r] + s;
        }
    } else if (bid == S1_N + S2_N){
        for (int i=tid; i<800; i+=256) out[i] = woutb[i & 1];
    } else {
        // cam[f][c][sp] f32 -> camT[f][sp][c] bf16, 64x64 LDS tile transpose
        const int f = bid - (S1_N + S2_N + 1);
        const int wave = tid>>6, lane = tid&63;
        const float* src = cam + (size_t)f*FRAME;
        unsigned short* dst = camT + (size_t)f*FRAME;
        for (int tc=0; tc<4; ++tc)
        for (int ts=0; ts<4; ++ts){
            const int c0t = tc*64, s0t = ts*64;
#pragma unroll
            for (int i=0;i<16;++i)
                tileL[wave*16+i][lane] = f2bf(src[(size_t)(c0t+wave*16+i)*256 + s0t + lane]);
            __syncthreads();
#pragma unroll
            for (int i=0;i<16;++i)
                dst[(size_t)(s0t+wave*16+i)*256 + c0t + lane] = tileL[lane][wave*16+i];
            __syncthreads();
        }
    }
}

// ================= K_CONV2: conv3x3 via MFMA + fused BN partials =================
// grid (4, 400): oc group x frame. 256 threads = 4 waves.
// R4-PROVEN config (161-164us): XSTR=40, launch_bounds(256,3), single launch.
// Measured dead ends: XSTR=36 (misalign+spill, 283us); L2-direct W (353us);
// reg-prefetch pipeline (spill, 287us); quarter-split (tail imbalance, +45us).
#define XSTR 40
__global__ __launch_bounds__(256, 3) void k_conv2(const float* __restrict__ cam,
                                                  const unsigned short* __restrict__ camT,
                                                  const unsigned short* __restrict__ wr,
                                                  const float* __restrict__ cb,
                                                  unsigned short* __restrict__ y,
                                                  float* __restrict__ Sp,
                                                  float* __restrict__ Sq){
    const int f   = blockIdx.y;
    const int oc0 = blockIdx.x * 64;
    const int tid = threadIdx.x;
    const int wv    = tid >> 6;
    const int quad  = (tid >> 4) & 3;
    const int wlane = tid & 15;

    __shared__ __align__(16) unsigned short Xl[324*XSTR];
    __shared__ __align__(16) unsigned short Al[192*XSTR];
    __shared__ float SredS[64], SredQ[64];

    for (int i = tid; i < 324*XSTR/2; i += 256) ((unsigned int*)Xl)[i] = 0u;
    if (tid < 64){ SredS[tid]=0.f; SredQ[tid]=0.f; }

    f32x4 acc[4][4];
#pragma unroll
    for (int mt=0; mt<4; ++mt){
        const int oc = oc0 + mt*16 + quad*4;
        f32x4 bv; bv[0]=cb[oc]; bv[1]=cb[oc+1]; bv[2]=cb[oc+2]; bv[3]=cb[oc+3];
#pragma unroll
        for (int nt=0; nt<4; ++nt) acc[mt][nt] = bv;
    }

    const int sp  = tid;
    const int spp = ((sp>>4)+1)*18 + (sp&15) + 1;
    const float* xs = cam + ((size_t)f*256)*256 + sp;
    const unsigned short* xt = camT ? (camT + (size_t)f*FRAME + (size_t)sp*256) : nullptr;

    for (int ck=0; ck<8; ++ck){
        const int c0 = ck*32;
        for (int tg=0; tg<3; ++tg){
            __syncthreads();
            if (tg == 0){
                if (xt){
                    // pre-converted bf16, channel-contiguous: 4 x 16B loads, zero VALU
                    const uint4* xc4 = (const uint4*)(xt + c0);
#pragma unroll
                    for (int jb=0; jb<4; ++jb)
                        *(uint4*)&Xl[spp*XSTR + jb*8] = xc4[jb];
                } else {
                    // fallback: fp32 gather + in-register convert (ws too small for camT)
                    const float* xc = xs + (size_t)c0*256;
#pragma unroll
                    for (int jb=0; jb<4; ++jb){
                        unsigned int q0,q1,q2,q3;
                        {
                            float a0=xc[(jb*8+0)*256], a1=xc[(jb*8+1)*256];
                            float a2=xc[(jb*8+2)*256], a3=xc[(jb*8+3)*256];
                            float a4=xc[(jb*8+4)*256], a5=xc[(jb*8+5)*256];
                            float a6=xc[(jb*8+6)*256], a7=xc[(jb*8+7)*256];
                            q0 = (unsigned int)f2bf(a0) | ((unsigned int)f2bf(a1)<<16);
                            q1 = (unsigned int)f2bf(a2) | ((unsigned int)f2bf(a3)<<16);
                            q2 = (unsigned int)f2bf(a4) | ((unsigned int)f2bf(a5)<<16);
                            q3 = (unsigned int)f2bf(a6) | ((unsigned int)f2bf(a7)<<16);
                        }
                        uint4 qv; qv.x=q0; qv.y=q1; qv.z=q2; qv.w=q3;
                        *(uint4*)&Xl[spp*XSTR + jb*8] = qv;
                    }
                }
            }
            if (tid < 192){
                const unsigned short* src = wr +
                    ((size_t)((tg*3 + (tid>>6))*256 + oc0 + (tid&63)))*256 + c0;
                const uint4* s4 = (const uint4*)src;
                uint4* dq = (uint4*)(Al + tid*XSTR);
                dq[0]=s4[0]; dq[1]=s4[1]; dq[2]=s4[2]; dq[3]=s4[3];
            }
            __syncthreads();
#pragma unroll
            for (int cc=0; cc<3; ++cc){
                bf16x8 af[4], bfr[4];
#pragma unroll
                for (int mt=0; mt<4; ++mt)
                    af[mt] = *(const bf16x8*)(Al + ((cc*64 + mt*16 + wlane)*XSTR + quad*8));
#pragma unroll
                for (int nt=0; nt<4; ++nt){
                    const int hh = wv*4 + nt;
                    const int pp = (hh + tg)*18 + wlane + cc;
                    bfr[nt] = *(const bf16x8*)(Xl + (pp*XSTR + quad*8));
                }
#pragma unroll
                for (int mt=0; mt<4; ++mt)
#pragma unroll
                    for (int nt=0; nt<4; ++nt)
                        acc[mt][nt] = __builtin_amdgcn_mfma_f32_16x16x32_bf16(
                            af[mt], bfr[nt], acc[mt][nt], 0, 0, 0);
            }
        }
    }

    // epilogue: y store (C/D layout col=lane&15, row=(lane>>4)*4+reg) [m89-verified]
#pragma unroll
    for (int mt=0; mt<4; ++mt){
        const int oc = oc0 + mt*16 + quad*4;
#pragma unroll
        for (int nt=0; nt<4; ++nt){
            const int p = (wv*4 + nt)*16 + wlane;
#pragma unroll
            for (int reg=0; reg<4; ++reg)
                y[((size_t)(f*256) + oc + reg)*256 + p] = f2bf(acc[mt][nt][reg]);
        }
    }
    // fused BN partial sums: per-(f,oc) sum over 256 spatial
    __syncthreads();
#pragma unroll
    for (int mt=0; mt<4; ++mt){
#pragma unroll
        for (int reg=0; reg<4; ++reg){
            float s=0.f, q=0.f;
#pragma unroll
            for (int nt=0; nt<4; ++nt){ float v=acc[mt][nt][reg]; s+=v; q+=v*v; }
#pragma unroll
            for (int off=1; off<16; off<<=1){ s += __shfl_xor(s,off,64); q += __shfl_xor(q,off,64); }
            if (wlane==0){
                atomicAdd(&SredS[mt*16 + quad*4 + reg], s);
                atomicAdd(&SredQ[mt*16 + quad*4 + reg], q);
            }
        }
    }
    __syncthreads();
    if (tid < 64){
        Sp[f*256 + oc0 + tid] = SredS[tid];
        Sq[f*256 + oc0 + tid] = SredQ[tid];
    }
}

// ================= K_BNFIN: finish BN stats -> scale/shift =================
__global__ __launch_bounds__(64) void k_bnfin(const float* __restrict__ Sp,
                                              const float* __restrict__ Sq,
                                              const float* __restrict__ gamma,
                                              const float* __restrict__ beta,
                                              float* __restrict__ scale,
                                              float* __restrict__ shift){
    const int c = blockIdx.x, lane = threadIdx.x;
    float s = 0.f, q = 0.f;
    for (int f=lane; f<NF; f+=64){ s += Sp[f*256 + c]; q += Sq[f*256 + c]; }
#pragma unroll
    for (int off=32; off; off>>=1){ s += __shfl_down(s,off,64); q += __shfl_down(q,off,64); }
    if (lane==0){
        const float invN = 1.0f/(float)(NF*256);
        float mean = s*invN;
        float var  = q*invN - mean*mean;
        float istd = rsqrtf(var + EPSB);
        float sc = gamma[c]*istd;
        scale[c] = sc;
        shift[c] = beta[c] - mean*sc;
    }
}

// ================= K_FRAME2: softmax/alpha/logp + ctx + x0 + fused Gp build =================
__global__ __launch_bounds__(256) void k_frame2(const unsigned short* __restrict__ y,
                                                const float* __restrict__ scale,
                                                const float* __restrict__ shift,
                                                const float* __restrict__ wattn,
                                                const float* __restrict__ wihT,
                                                float* __restrict__ d_out,
                                                float* __restrict__ Gp,
                                                float* __restrict__ x0g){
    const int f = blockIdx.x, tid = threadIdx.x;
    const int b = f / TT, t = f - b*TT;
    const int wave = tid>>6, lane = tid&63;
    __shared__ float fdotL[256], alphaL[256], x0acc[256], wattnL[256];
    __shared__ float ctxP[4][256];
    __shared__ float redM[4], redS[4];
    wattnL[tid] = wattn[tid];
    x0acc[tid] = 0.f;
    __syncthreads();
    const bool isT0 = (t==0);
    const float wl0 = wattnL[lane*4+0], wl1 = wattnL[lane*4+1];
    const float wl2 = wattnL[lane*4+2], wl3 = wattnL[lane*4+3];
    const ushort4* y4 = (const ushort4*)(y + (size_t)f*FRAME);
    for (int ci=0; ci<64; ++ci){
        int c = wave + ci*4;
        ushort4 u = y4[c*64 + lane];
        float sc = scale[c], sh = shift[c];
        float v0 = fmaxf(fmaf(bf2f(u.x),sc,sh),0.f);
        float v1 = fmaxf(fmaf(bf2f(u.y),sc,sh),0.f);
        float v2 = fmaxf(fmaf(bf2f(u.z),sc,sh),0.f);
        float v3 = fmaxf(fmaf(bf2f(u.w),sc,sh),0.f);
        float s = v0*wl0 + v1*wl1 + v2*wl2 + v3*wl3;
#pragma unroll
        for (int off=32; off; off>>=1) s += __shfl_down(s,off,64);
        if (lane==0) fdotL[c] = s;
        if (isT0){
            atomicAdd(&x0acc[lane*4+0], v0);
            atomicAdd(&x0acc[lane*4+1], v1);
            atomicAdd(&x0acc[lane*4+2], v2);
            atomicAdd(&x0acc[lane*4+3], v3);
        }
    }
    __syncthreads();
    float v = fdotL[tid];
    float m = v;
#pragma unroll
    for (int off=32; off; off>>=1) m = fmaxf(m, __shfl_down(m,off,64));
    if (lane==0) redM[wave]=m;
    __syncthreads();
    m = fmaxf(fmaxf(redM[0],redM[1]),fmaxf(redM[2],redM[3]));
    float e = __expf(v-m);
    float ss = e;
#pragma unroll
    for (int off=32; off; off>>=1) ss += __shfl_down(ss,off,64);
    if (lane==0) redS[wave]=ss;
    __syncthreads();
    float S = redS[0]+redS[1]+redS[2]+redS[3];
    float logS = logf(S);
    float alpha = e / S;
    d_out[800    + ((t*BB)+b)*256 + tid] = alpha;
    d_out[103200 + ((t*BB)+b)*256 + tid] = v - m - logS;
    alphaL[tid] = alpha;
    if (isT0) x0g[b*256+tid] = x0acc[tid];
    __syncthreads();
    // ctx pass: wave-partial over 64 channels, vectorized ushort4, 4-way LDS reduce
    {
        float ca0=0.f, ca1=0.f, ca2=0.f, ca3=0.f;
        for (int ci=0; ci<64; ++ci){
            int c = wave + ci*4;
            ushort4 u = y4[c*64 + lane];
            float sc = scale[c], sh = shift[c];
            float al = alphaL[c];
            ca0 = fmaf(fmaxf(fmaf(bf2f(u.x),sc,sh),0.f), al, ca0);
            ca1 = fmaf(fmaxf(fmaf(bf2f(u.y),sc,sh),0.f), al, ca1);
            ca2 = fmaf(fmaxf(fmaf(bf2f(u.z),sc,sh),0.f), al, ca2);
            ca3 = fmaf(fmaxf(fmaf(bf2f(u.w),sc,sh),0.f), al, ca3);
        }
        ctxP[wave][lane*4+0] = ca0;
        ctxP[wave][lane*4+1] = ca1;
        ctxP[wave][lane*4+2] = ca2;
        ctxP[wave][lane*4+3] = ca3;
    }
    __syncthreads();
    fdotL[tid] = ctxP[0][tid] + ctxP[1][tid] + ctxP[2][tid] + ctxP[3][tid];
    __syncthreads();
    // fused gperm via wihT broadcast-GEMV: thread owns rows tid*4..tid*4+3.
    float accg[4] = {0.f, 0.f, 0.f, 0.f};
    const float4* wT4 = (const float4*)wihT;
#pragma unroll 8
    for (int k=0; k<256; ++k){
        float ck = fdotL[k];
        float4 wv = wT4[k*256 + tid];
        accg[0] = fmaf(ck, wv.x, accg[0]);
        accg[1] = fmaf(ck, wv.y, accg[1]);
        accg[2] = fmaf(ck, wv.z, accg[2]);
        accg[3] = fmaf(ck, wv.w, accg[3]);
    }
    float* gout = Gp + (size_t)t*4096;
#pragma unroll
    for (int j=0; j<4; ++j){
        int r = tid*4 + j;
        int g = r >> 8, u = r & 255;
        int wvv = u >> 5, e = (u >> 4) & 1, nn = u & 15;
        gout[(wvv*64 + b*16 + nn)*8 + e*4 + g] = accg[j];
    }
}

// ================= K_INIT: hx/cx = tanh(x0 @ W.T + b) =================
__global__ __launch_bounds__(256) void k_init(const float* __restrict__ x0g,
                                              const float* __restrict__ ihw,
                                              const float* __restrict__ ihb,
                                              const float* __restrict__ icw,
                                              const float* __restrict__ icb,
                                              float* __restrict__ hxg,
                                              float* __restrict__ cxg){
    const int b = blockIdx.x >> 1, which = blockIdx.x & 1;
    const int tid = threadIdx.x, wave = tid>>6, lane = tid&63;
    __shared__ float xL[256];
    xL[tid] = x0g[b*256+tid] * (1.0f/256.0f);
    __syncthreads();
    const float* wmat = which ? icw : ihw;
    const float* bias = which ? icb : ihb;
    float* dst = which ? cxg : hxg;
    const float4* x4 = (const float4*)xL;
    float4 xv = x4[lane];
    const float4* w4 = (const float4*)wmat;
    for (int r=wave; r<256; r+=4){
        float4 wv = w4[r*64+lane];
        float s = xv.x*wv.x + xv.y*wv.y + xv.z*wv.z + xv.w*wv.w;
#pragma unroll
        for (int off=32; off; off>>=1) s += __shfl_down(s,off,64);
        if (lane==0) dst[b*256+r] = tanhf(s + bias[r]);
    }
}

// ================= K_SCAN: single-WG persistent LSTM scan — 16 waves, predL (best) ===
// Measured: 8-wave predL 142us; 16-wave predL 129-132us (BEST); global-hist 142us
// (vmcnt drain at barrier — reverted). Step cost = DS burst (~1760cy) + MFMA burst
// (~1300cy), phase-aligned by the barrier (cannot overlap) — structural floor.
__global__ __launch_bounds__(1024) void k_scan(const int8_t* __restrict__ Wq,
                                               const float* __restrict__ dqs,
                                               const float* __restrict__ biasg,
                                               const float* __restrict__ Gp,
                                               const float* __restrict__ cxg,
                                               const float* __restrict__ hxg,
                                               const float* __restrict__ woutw,
                                               float* __restrict__ out){
    const int tid  = threadIdx.x;
    const int wv2  = tid >> 6, lane = tid & 63;
    const int q    = lane >> 4, n = lane & 15;
    const int w8   = wv2 >> 1, e = wv2 & 1;

    __shared__ __align__(16) int8_t hxq[2][4*272];
    __shared__ float predL[TT*128];   // [t][wv2*8 + q*2 + j], per-wave slots (no races)

    // unit owned by this lane
    const int u = w8*32 + e*16 + n;

    i32x4 bfrag[4][4];
#pragma unroll
    for (int g=0; g<4; ++g)
#pragma unroll
        for (int kt=0; kt<4; ++kt)
            bfrag[g][kt] = *(const i32x4*)(Wq +
                ((size_t)(((w8*8 + g*2 + e)*4 + kt)*4 + q)*16 + n)*16);

    float cx = cxg[q*256 + u];
    const float w0 = woutw[u], w1 = woutw[256 + u];
    float dq[4], bb[4];
#pragma unroll
    for (int g=0; g<4; ++g){
        dq[g] = dqs[g*256 + u];
        bb[g] = biasg[g*256 + u];
    }

    {
        const int b0 = tid >> 8, u0 = tid & 255;
        hxq[0][b0*272 + u0] = q8(hxg[b0*256 + u0] * 127.0f);
    }
    const size_t gbase = (size_t)((w8*64 + q*16 + n)*8 + e*4);
    float4 gA = *(const float4*)(Gp + gbase);
    __syncthreads();

    for (int t=0; t<TT; ++t){
        const int tn = (t+1 < TT) ? t+1 : t;
        float4 nA = *(const float4*)(Gp + (size_t)tn*4096 + gbase);

        const int8_t* hb = hxq[t & 1];
        i32x4 afr[4];
#pragma unroll
        for (int kt=0; kt<4; ++kt)
            afr[kt] = *(const i32x4*)(hb + (n >> 2)*272 + kt*64 + q*16);

        i32x4 acc[4];
#pragma unroll
        for (int g=0; g<4; ++g){ acc[g][0]=0; acc[g][1]=0; acc[g][2]=0; acc[g][3]=0; }
#pragma unroll
        for (int g=0; g<4; ++g)
#pragma unroll
            for (int kt=0; kt<4; ++kt)
                acc[g] = __builtin_amdgcn_mfma_i32_16x16x64_i8(afr[kt], bfrag[g][kt], acc[g], 0, 0, 0);

        float gi = (float)acc[0][0]*dq[0] + gA.x + bb[0];
        float gf = (float)acc[1][0]*dq[1] + gA.y + bb[1];
        float gg = (float)acc[2][0]*dq[2] + gA.z + bb[2];
        float go = (float)acc[3][0]*dq[3] + gA.w + bb[3];

        float cn = fsigm(gf)*cx + fsigm(gi)*ftanh(gg);
        float hn = fsigm(go)*ftanh(cn);
        cx = cn;

        hxq[(t+1) & 1][q*272 + u] = q8(hn * 127.0f);

        float p0 = hn*w0;
        float p1 = hn*w1;
#pragma unroll
        for (int off=1; off<16; off<<=1){
            p0 += __shfl_xor(p0, off, 64);
            p1 += __shfl_xor(p1, off, 64);
        }
        if (n == 0){
            predL[t*128 + wv2*8 + q*2 + 0] = p0;
            predL[t*128 + wv2*8 + q*2 + 1] = p1;
        }
        gA = nA;
        __syncthreads();
    }
    // epilogue: reduce per-wave slots -> out (out pre-loaded with woutb by k_prep)
    if (tid < TT*8){
        const int t = tid >> 3, j = tid & 7;
        float s = 0.f;
#pragma unroll
        for (int w16 = 0; w16 < 16; ++w16) s += predL[t*128 + w16*8 + j];
        out[tid] += s;
    }
}

extern "C" void kernel_launch(void* const* d_in, const int* in_sizes, int n_in,
                              void* d_out, int out_size, void* d_ws, size_t ws_size,
                              hipStream_t stream){
    const float* cam   = (const float*)d_in[0];
    const float* convw = (const float*)d_in[1];
    const float* convb = (const float*)d_in[2];
    const float* gamma = (const float*)d_in[3];
    const float* beta  = (const float*)d_in[4];
    const float* ihw   = (const float*)d_in[5];
    const float* ihb   = (const float*)d_in[6];
    const float* icw   = (const float*)d_in[7];
    const float* icb   = (const float*)d_in[8];
    const float* ww    = (const float*)d_in[9];
    const float* wb    = (const float*)d_in[10];
    const float* wattn = (const float*)d_in[11];
    // d_in[12] = wattn_b: unused (softmax is shift-invariant)
    const float* wih   = (const float*)d_in[13];
    const float* whh   = (const float*)d_in[14];
    const float* bih   = (const float*)d_in[15];
    const float* bhh   = (const float*)d_in[16];
    const float* woutw = (const float*)d_in[17];
    const float* woutb = (const float*)d_in[18];
    float* out = (float*)d_out;

    char* wsb = (char*)d_ws;
    size_t off = 0;
    auto alloc = [&](size_t bytes)->void*{
        void* p = wsb + off; off += (bytes + 255) & ~(size_t)255; return p;
    };
    unsigned short* y   = (unsigned short*)alloc((size_t)NF*FRAME*2);
    unsigned short* wr2 = (unsigned short*)alloc((size_t)589824*2);
    int8_t* Wq      = (int8_t*)alloc((size_t)262144);
    float* dqs      = (float*)alloc(1024*4);
    float* Sp       = (float*)alloc((size_t)NF*256*4);
    float* Sq       = (float*)alloc((size_t)NF*256*4);
    float* scale    = (float*)alloc(256*4);
    float* shift    = (float*)alloc(256*4);
    float* x0g      = (float*)alloc(1024*4);
    float* Gp       = (float*)alloc((size_t)TT*4096*4);
    float* biasg    = (float*)alloc(1024*4);
    float* hxg      = (float*)alloc(1024*4);
    float* cxg      = (float*)alloc(1024*4);
    float* wihT     = (float*)alloc((size_t)262144*4);   // [k=256][r=1024] transpose
    // camT only if workspace allows (52.4 MB): guarded fallback keeps correctness
    unsigned short* camT = nullptr;
    if (ws_size >= off + (size_t)NF*FRAME*2 + 256)
        camT = (unsigned short*)alloc((size_t)NF*FRAME*2);

    const int prep_blocks = S1_N + S2_N + 1 + (camT ? NF : 0);
    hipLaunchKernelGGL(k_prep, dim3(prep_blocks), dim3(256), 0, stream,
                       convw, wih, whh, ww, wb, bih, bhh, woutb, cam,
                       wr2, Wq, dqs, biasg, wihT, camT, out);
    hipLaunchKernelGGL(k_conv2, dim3(4, NF), dim3(256), 0, stream, cam, camT, wr2, convb, y, Sp, Sq);
    hipLaunchKernelGGL(k_bnfin, dim3(256), dim3(64), 0, stream, Sp, Sq, gamma, beta, scale, shift);
    hipLaunchKernelGGL(k_frame2, dim3(NF), dim3(256), 0, stream, y, scale, shift, wattn, wihT, out, Gp, x0g);
    hipLaunchKernelGGL(k_init, dim3(8), dim3(256), 0, stream, x0g, ihw, ihb, icw, icb, hxg, cxg);
    hipLaunchKernelGGL(k_scan, dim3(1), dim3(1024), 0, stream,
                       Wq, dqs, biasg, Gp, cxg, hxg, woutw, out);
}